// Round 8
// baseline (346.586 us; speedup 1.0000x reference)
//
#include <hip/hip_runtime.h>
#include <math.h>

#define TT    512
#define BB    512
#define HID   32
#define EMB   32
#define FFD   16
#define NCLS  7
#define VOCABN 1000

typedef float v2f __attribute__((ext_vector_type(2)));
typedef float v4f __attribute__((ext_vector_type(4)));

#define NLOG2E  (-1.4426950408889634f)
#define N2LOG2E (-2.8853900817779268f)

__device__ __forceinline__ float rl(float v, int k) {
    return __int_as_float(__builtin_amdgcn_readlane(__float_as_int(v), k));
}
__device__ __forceinline__ float fast_rcp(float x) {
#if defined(__has_builtin)
#if __has_builtin(__builtin_amdgcn_rcpf)
    return __builtin_amdgcn_rcpf(x);
#else
    return 1.0f / x;
#endif
#else
    return 1.0f / x;
#endif
}
__device__ __forceinline__ float sigf(float x) { return fast_rcp(1.0f + __expf(-x)); }
__device__ __forceinline__ float tanh_fast(float x) { return 2.0f * sigf(2.0f * x) - 1.0f; }

__device__ __forceinline__ v2f fma2(v2f a, v2f b, v2f c) {
#if defined(__has_builtin)
#if __has_builtin(__builtin_elementwise_fma)
    return __builtin_elementwise_fma(a, b, c);
#else
    v2f r; r.x = fmaf(a.x, b.x, c.x); r.y = fmaf(a.y, b.y, c.y); return r;
#endif
#else
    v2f r; r.x = fmaf(a.x, b.x, c.x); r.y = fmaf(a.y, b.y, c.y); return r;
#endif
}

// Cross-half (lane ^ 32) exchange via v_permlane32_swap_b32 (VALU).
// Orientation-proof: r[0]^r[1]^self == partner.
__device__ __forceinline__ float xhalf_swap(float v) {
#if defined(__has_builtin)
#if __has_builtin(__builtin_amdgcn_permlane32_swap)
    const unsigned u = __float_as_uint(v);
    auto r = __builtin_amdgcn_permlane32_swap(u, u, false, false);
    return __uint_as_float((r[0] ^ r[1]) ^ u);
#else
    return __shfl_xor(v, 32);
#endif
#else
    return __shfl_xor(v, 32);
#endif
}

// per-component vector helpers (trans ops scalarize into adjacent insts ->
// the two chains' streams interleave by construction)
__device__ __forceinline__ v2f exp2v(v2f a) {
    v2f r; r.x = __builtin_exp2f(a.x); r.y = __builtin_exp2f(a.y); return r;
}
__device__ __forceinline__ v2f rcpv(v2f a) {
    v2f r; r.x = fast_rcp(a.x); r.y = fast_rcp(a.y); return r;
}
__device__ __forceinline__ v2f swapv(v2f a) {
    v2f r; r.x = xhalf_swap(a.x); r.y = xhalf_swap(a.y); return r;
}

// xg_table[v][j] = {W_ih[j,:]·emb[v,:]+b[j], W_ih[j+64,:]·emb[v,:]+b[j+64]}
// scaled!=0: entries pre-multiplied by activation log2-scales (see lstm_recp).
__global__ __launch_bounds__(64) void build_xg(
    const float* __restrict__ emb, const float* __restrict__ W_ih,
    const float* __restrict__ b_ih, const float* __restrict__ b_hh,
    float2* __restrict__ tab, int scaled)
{
    const int v = blockIdx.x;
    const int j = threadIdx.x;
    const float* e  = emb + v * EMB;
    const float* w0 = W_ih + j * EMB;
    const float* w1 = W_ih + (j + 64) * EMB;
    float a0 = b_ih[j]      + b_hh[j];
    float a1 = b_ih[j + 64] + b_hh[j + 64];
    #pragma unroll
    for (int k = 0; k < EMB; ++k) {
        const float ek = e[k];
        a0 = fmaf(w0[k], ek, a0);
        a1 = fmaf(w1[k], ek, a1);
    }
    float s0 = 1.0f, s1 = 1.0f;
    if (scaled) { s0 = NLOG2E; s1 = (j < 32) ? N2LOG2E : NLOG2E; }
    tab[v * 64 + j] = make_float2(a0 * s0, a1 * s1);
}

// Serial recurrence, TWO chains PACKED per wave (chain0 in .x, chain1 in .y of
// every v2f). R6 EVIDENCE: two chains as sequential code = compiler serializes
// (pair 1247 ~ 2x689). R7 EVIDENCE: in-register butterfly loses to the LDS
// broadcast (in-order wave, swizzle depth). THIS version forces interleave by
// DATA-PACKING: every pk_fma / packed add / select carries both chains, the
// scalarized trans pairs alternate chains. LDS layout shp[k]={h0[k],h1[k]}:
// one ds_write_b64 publishes both h's; 16 uniform ds_read_b128 deliver
// ready-made chain-pair operands. Weights pre-duplicated {w,w} (128 VGPR;
// waves_per_eu(1,1) keeps them resident - R4 evidence). Grid BB/2.
__global__ __launch_bounds__(64)
__attribute__((amdgpu_waves_per_eu(1, 1)))
void lstm_recp(
    const int* __restrict__ x, const float2* __restrict__ tab,
    const float* __restrict__ W_hh, float* __restrict__ hsout)
{
    const int b0 = blockIdx.x * 2;
    const int b1 = b0 + 1;
    const int j  = threadIdx.x;
    const int m  = j & 31;
    const bool lo = j < 32;

    __shared__ __align__(16) float2 shp[HID];   // {h0[k], h1[k]}

    // ---- W_hh rows j, j+64 -> 64 duplicated v2f {w,w}, pre-scaled ----
    const float fA = NLOG2E;
    const float fB = lo ? N2LOG2E : NLOG2E;
    const float* WrA = W_hh + (size_t)j * HID;
    const float* WrB = W_hh + (size_t)(j + 64) * HID;
    v2f wda0,wda1,wda2,wda3,wda4,wda5,wda6,wda7,wda8,wda9,wda10,wda11,wda12,wda13,wda14,wda15,
        wda16,wda17,wda18,wda19,wda20,wda21,wda22,wda23,wda24,wda25,wda26,wda27,wda28,wda29,wda30,wda31;
    v2f wdb0,wdb1,wdb2,wdb3,wdb4,wdb5,wdb6,wdb7,wdb8,wdb9,wdb10,wdb11,wdb12,wdb13,wdb14,wdb15,
        wdb16,wdb17,wdb18,wdb19,wdb20,wdb21,wdb22,wdb23,wdb24,wdb25,wdb26,wdb27,wdb28,wdb29,wdb30,wdb31;
    #define LDW(k) { const float a_ = WrA[k] * fA, b_ = WrB[k] * fB; \
                     wda##k = (v2f){a_, a_}; wdb##k = (v2f){b_, b_}; }
    LDW(0)  LDW(1)  LDW(2)  LDW(3)  LDW(4)  LDW(5)  LDW(6)  LDW(7)
    LDW(8)  LDW(9)  LDW(10) LDW(11) LDW(12) LDW(13) LDW(14) LDW(15)
    LDW(16) LDW(17) LDW(18) LDW(19) LDW(20) LDW(21) LDW(22) LDW(23)
    LDW(24) LDW(25) LDW(26) LDW(27) LDW(28) LDW(29) LDW(30) LDW(31)
    #undef LDW

    v2f c = {0.f, 0.f};
    float* hrow0 = hsout + (size_t)b0 * TT * HID;
    float* hrow1 = hsout + (size_t)b1 * TT * HID;

    // t=0 broadcast source: h=0 for both chains
    *(v2f*)(shp + m) = (v2f){0.f, 0.f};

    // ---- prologue: block-0 xg in registers, block-1 indices staged ----
    int xiB0[8], xiB1[8];
    float2 cxg0[8], cxg1[8];
    {
        int xi00[8], xi01[8];
        #pragma unroll
        for (int u = 0; u < 8; ++u) { xi00[u] = x[u * BB + b0]; xi01[u] = x[u * BB + b1]; }
        #pragma unroll
        for (int u = 0; u < 8; ++u) { xiB0[u] = x[(8 + u) * BB + b0]; xiB1[u] = x[(8 + u) * BB + b1]; }
        #pragma unroll
        for (int u = 0; u < 8; ++u) {
            cxg0[u] = tab[(size_t)xi00[u] * 64 + j];
            cxg1[u] = tab[(size_t)xi01[u] * 64 + j];
        }
    }

    const v2f one2 = {1.f, 1.f};
    const v2f two2 = {2.f, 2.f};
    const v2f mone2 = {-1.f, -1.f};
    const v2f nl2 = {N2LOG2E, N2LOG2E};

    for (int t8 = 0; t8 < TT / 8; ++t8) {
        // next-block gathers + next-next-block index loads up front;
        // consumed after the 8 serial steps below -> latency fully hidden.
        float2 nxg0[8], nxg1[8];
        #pragma unroll
        for (int u = 0; u < 8; ++u) {
            nxg0[u] = tab[(size_t)xiB0[u] * 64 + j];
            nxg1[u] = tab[(size_t)xiB1[u] * 64 + j];
        }
        int xiN0[8], xiN1[8];
        const int nb2 = (t8 + 2 < TT / 8) ? (t8 + 2) * 8 : 0;  // tail: dead but safe
        #pragma unroll
        for (int u = 0; u < 8; ++u) {
            xiN0[u] = x[(nb2 + u) * BB + b0];
            xiN1[u] = x[(nb2 + u) * BB + b1];
        }

        #pragma unroll
        for (int u = 0; u < 8; ++u) {
            // broadcast read: 16 uniform ds_read_b128; rq covers k=2q (lo pair)
            // and k=2q+1 (hi pair), each pair = {h0[k], h1[k]}
            const v4f* sp = (const v4f*)shp;
            const v4f r0  = sp[0],  r1  = sp[1],  r2  = sp[2],  r3  = sp[3];
            const v4f r4  = sp[4],  r5  = sp[5],  r6  = sp[6],  r7  = sp[7];
            const v4f r8  = sp[8],  r9  = sp[9],  r10 = sp[10], r11 = sp[11];
            const v4f r12 = sp[12], r13 = sp[13], r14 = sp[14], r15 = sp[15];

            // dot: 64 pk_fma (both chains per inst), 4 accumulators per row
            v2f pA0 = {cxg0[u].x, cxg1[u].x}, pA1 = {0.f, 0.f}, pA2 = {0.f, 0.f}, pA3 = {0.f, 0.f};
            v2f pB0 = {cxg0[u].y, cxg1[u].y}, pB1 = {0.f, 0.f}, pB2 = {0.f, 0.f}, pB3 = {0.f, 0.f};
            pA0 = fma2(wda0,  r0.lo,  pA0);  pB0 = fma2(wdb0,  r0.lo,  pB0);
            pA1 = fma2(wda1,  r0.hi,  pA1);  pB1 = fma2(wdb1,  r0.hi,  pB1);
            pA2 = fma2(wda2,  r1.lo,  pA2);  pB2 = fma2(wdb2,  r1.lo,  pB2);
            pA3 = fma2(wda3,  r1.hi,  pA3);  pB3 = fma2(wdb3,  r1.hi,  pB3);
            pA0 = fma2(wda4,  r2.lo,  pA0);  pB0 = fma2(wdb4,  r2.lo,  pB0);
            pA1 = fma2(wda5,  r2.hi,  pA1);  pB1 = fma2(wdb5,  r2.hi,  pB1);
            pA2 = fma2(wda6,  r3.lo,  pA2);  pB2 = fma2(wdb6,  r3.lo,  pB2);
            pA3 = fma2(wda7,  r3.hi,  pA3);  pB3 = fma2(wdb7,  r3.hi,  pB3);
            pA0 = fma2(wda8,  r4.lo,  pA0);  pB0 = fma2(wdb8,  r4.lo,  pB0);
            pA1 = fma2(wda9,  r4.hi,  pA1);  pB1 = fma2(wdb9,  r4.hi,  pB1);
            pA2 = fma2(wda10, r5.lo,  pA2);  pB2 = fma2(wdb10, r5.lo,  pB2);
            pA3 = fma2(wda11, r5.hi,  pA3);  pB3 = fma2(wdb11, r5.hi,  pB3);
            pA0 = fma2(wda12, r6.lo,  pA0);  pB0 = fma2(wdb12, r6.lo,  pB0);
            pA1 = fma2(wda13, r6.hi,  pA1);  pB1 = fma2(wdb13, r6.hi,  pB1);
            pA2 = fma2(wda14, r7.lo,  pA2);  pB2 = fma2(wdb14, r7.lo,  pB2);
            pA3 = fma2(wda15, r7.hi,  pA3);  pB3 = fma2(wdb15, r7.hi,  pB3);
            pA0 = fma2(wda16, r8.lo,  pA0);  pB0 = fma2(wdb16, r8.lo,  pB0);
            pA1 = fma2(wda17, r8.hi,  pA1);  pB1 = fma2(wdb17, r8.hi,  pB1);
            pA2 = fma2(wda18, r9.lo,  pA2);  pB2 = fma2(wdb18, r9.lo,  pB2);
            pA3 = fma2(wda19, r9.hi,  pA3);  pB3 = fma2(wdb19, r9.hi,  pB3);
            pA0 = fma2(wda20, r10.lo, pA0);  pB0 = fma2(wdb20, r10.lo, pB0);
            pA1 = fma2(wda21, r10.hi, pA1);  pB1 = fma2(wdb21, r10.hi, pB1);
            pA2 = fma2(wda22, r11.lo, pA2);  pB2 = fma2(wdb22, r11.lo, pB2);
            pA3 = fma2(wda23, r11.hi, pA3);  pB3 = fma2(wdb23, r11.hi, pB3);
            pA0 = fma2(wda24, r12.lo, pA0);  pB0 = fma2(wdb24, r12.lo, pB0);
            pA1 = fma2(wda25, r12.hi, pA1);  pB1 = fma2(wdb25, r12.hi, pB1);
            pA2 = fma2(wda26, r13.lo, pA2);  pB2 = fma2(wdb26, r13.lo, pB2);
            pA3 = fma2(wda27, r13.hi, pA3);  pB3 = fma2(wdb27, r13.hi, pB3);
            pA0 = fma2(wda28, r14.lo, pA0);  pB0 = fma2(wdb28, r14.lo, pB0);
            pA1 = fma2(wda29, r14.hi, pA1);  pB1 = fma2(wdb29, r14.hi, pB1);
            pA2 = fma2(wda30, r15.lo, pA2);  pB2 = fma2(wdb30, r15.lo, pB2);
            pA3 = fma2(wda31, r15.hi, pA3);  pB3 = fma2(wdb31, r15.hi, pB3);
            const v2f accA = (pA0 + pA1) + (pA2 + pA3);  // pre-scaled by -log2e
            const v2f accB = (pB0 + pB1) + (pB2 + pB3);  // -2log2e (g) / -log2e (o)

            // activations: trans ops scalarize -> chain pair interleaves
            const v2f actA = rcpv(one2 + exp2v(accA));          // i (lo) / f (hi)
            const v2f sgB  = rcpv(one2 + exp2v(accB));
            const v2f actB = lo ? fma2(two2, sgB, mone2) : sgB; // g (lo) / o (hi)
            const v2f oA = swapv(actA);
            const v2f oB = swapv(actB);
            const v2f gi = lo ? actA : oA;
            const v2f gf = lo ? oA   : actA;
            const v2f gg = lo ? actB : oB;
            const v2f go = lo ? oB   : actB;
            c = fma2(gf, c, gi * gg);
            const v2f tc = fma2(two2, rcpv(one2 + exp2v(c * nl2)), mone2); // tanh(c)
            const v2f h = go * tc;

            // publish next-step broadcast source (one b64 write, both chains);
            // lanes 32-63 duplicate same addr/value - benign.
            *(v2f*)(shp + m) = h;

            // fire-and-forget coalesced global stores (128B per chain)
            hrow0[(t8 * 8 + u) * HID + m] = h.x;
            hrow1[(t8 * 8 + u) * HID + m] = h.y;
        }

        // rotate double buffers
        #pragma unroll
        for (int u = 0; u < 8; ++u) {
            cxg0[u] = nxg0[u]; xiB0[u] = xiN0[u];
            cxg1[u] = nxg1[u]; xiB1[u] = xiN1[u];
        }
    }
}

// FF + logits + softmax-over-t, one block per b, 2 timesteps per thread.
__global__ __launch_bounds__(256) void ff_softmax(
    const float* __restrict__ hs,
    const float* __restrict__ W1, const float* __restrict__ b1,
    const float* __restrict__ W2, const float* __restrict__ b2,
    float* __restrict__ out)
{
    const int b    = blockIdx.x;
    const int tid  = threadIdx.x;
    const int lane = tid & 63, wv = tid >> 6;
    const int t0   = tid * 2;

    __shared__ float redM[4][NCLS];
    __shared__ float redS[4][NCLS];

    float4 hv[16];
    const float4* hb = (const float4*)(hs + ((size_t)b * TT + t0) * HID);
    #pragma unroll
    for (int q = 0; q < 16; ++q) hv[q] = hb[q];

    float lg[2][NCLS];
    #pragma unroll
    for (int r = 0; r < 2; ++r) {
        const float* hr = (const float*)(hv + 8 * r);
        float z[FFD];
        #pragma unroll
        for (int f = 0; f < FFD; ++f) {
            float a = b1[f];
            #pragma unroll
            for (int k = 0; k < HID; ++k) a = fmaf(W1[f * HID + k], hr[k], a);
            z[f] = fmaxf(a, 0.f);
        }
        #pragma unroll
        for (int cc = 0; cc < NCLS; ++cc) {
            float a = b2[cc];
            #pragma unroll
            for (int f = 0; f < FFD; ++f) a = fmaf(W2[cc * FFD + f], z[f], a);
            lg[r][cc] = a;
        }
    }

    float M[NCLS], S[NCLS];
    #pragma unroll
    for (int cc = 0; cc < NCLS; ++cc) {
        float mm = fmaxf(lg[0][cc], lg[1][cc]);
        #pragma unroll
        for (int off = 32; off; off >>= 1) mm = fmaxf(mm, __shfl_xor(mm, off));
        if (lane == 0) redM[wv][cc] = mm;
    }
    __syncthreads();
    #pragma unroll
    for (int cc = 0; cc < NCLS; ++cc)
        M[cc] = fmaxf(fmaxf(redM[0][cc], redM[1][cc]), fmaxf(redM[2][cc], redM[3][cc]));

    #pragma unroll
    for (int cc = 0; cc < NCLS; ++cc) {
        float ss = __expf(lg[0][cc] - M[cc]) + __expf(lg[1][cc] - M[cc]);
        #pragma unroll
        for (int off = 32; off; off >>= 1) ss += __shfl_xor(ss, off);
        if (lane == 0) redS[wv][cc] = ss;
    }
    __syncthreads();
    #pragma unroll
    for (int cc = 0; cc < NCLS; ++cc)
        S[cc] = (redS[0][cc] + redS[1][cc]) + (redS[2][cc] + redS[3][cc]);

    #pragma unroll
    for (int r = 0; r < 2; ++r) {
        float* o = out + ((size_t)(t0 + r) * BB + b) * NCLS;
        #pragma unroll
        for (int cc = 0; cc < NCLS; ++cc)
            o[cc] = __expf(lg[r][cc] - M[cc]) * fast_rcp(S[cc]);
    }
}

// ---------------- round-2 verified fused kernel (fallback paths) ----------------
template <bool TAB>
__global__ __launch_bounds__(64) void lstm_all(
    const int* __restrict__ x, const float* __restrict__ emb,
    const float* __restrict__ W_ih, const float* __restrict__ W_hh,
    const float* __restrict__ b_ih, const float* __restrict__ b_hh,
    const float* __restrict__ W1, const float* __restrict__ b1,
    const float* __restrict__ W2, const float* __restrict__ b2,
    const float2* __restrict__ tab, float* __restrict__ out)
{
    const int b  = blockIdx.x;
    const int j  = threadIdx.x;
    const int m  = j & 31;
    const bool lo = j < 32;
    const int rA = j, rB = j + 64;

    float whhA[HID], whhB[HID];
    #pragma unroll
    for (int k = 0; k < HID; k += 4) {
        float4 a;
        a = *(const float4*)(W_hh + rA * HID + k); whhA[k]=a.x; whhA[k+1]=a.y; whhA[k+2]=a.z; whhA[k+3]=a.w;
        a = *(const float4*)(W_hh + rB * HID + k); whhB[k]=a.x; whhB[k+1]=a.y; whhB[k+2]=a.z; whhB[k+3]=a.w;
    }
    float wihA[HID], wihB[HID];
    float biasA = 0.f, biasB = 0.f;
    if constexpr (!TAB) {
        #pragma unroll
        for (int k = 0; k < HID; k += 4) {
            float4 a;
            a = *(const float4*)(W_ih + rA * HID + k); wihA[k]=a.x; wihA[k+1]=a.y; wihA[k+2]=a.z; wihA[k+3]=a.w;
            a = *(const float4*)(W_ih + rB * HID + k); wihB[k]=a.x; wihB[k+1]=a.y; wihB[k+2]=a.z; wihB[k+3]=a.w;
        }
        biasA = b_ih[rA] + b_hh[rA];
        biasB = b_ih[rB] + b_hh[rB];
    }
    const int f16 = j & 15;
    float w1r[HID];
    #pragma unroll
    for (int k = 0; k < HID; ++k) w1r[k] = W1[f16 * HID + k];
    const int cls = j & 7;
    const int c7  = (cls < NCLS) ? cls : 0;
    float w2r[FFD];
    #pragma unroll
    for (int f = 0; f < FFD; ++f) w2r[f] = W2[c7 * FFD + f];
    const float b1v = b1[f16];
    const float b2v = b2[c7];

    float h = 0.f, c = 0.f;
    float mrun = -3.0e38f, srun = 0.f;

    auto gates = [&](float accA, float accB) {
        const float actA = sigf(accA);
        const float sB   = lo ? 2.0f * accB : accB;
        const float sgB  = sigf(sB);
        const float actB = lo ? 2.0f * sgB - 1.0f : sgB;
        const float oA = __shfl_xor(actA, 32);
        const float oB = __shfl_xor(actB, 32);
        const float gi = lo ? actA : oA;
        const float gf = lo ? oA   : actA;
        const float gg = lo ? actB : oB;
        const float go = lo ? oB   : actB;
        c = fmaf(gf, c, gi * gg);
        h = go * tanh_fast(c);
    };

    auto ff_head = [&](int t_out, const float* hsv) {
        float z0 = b1v, z1 = 0.f;
        #pragma unroll
        for (int k = 0; k < HID; k += 2) {
            z0 = fmaf(w1r[k],     hsv[k],     z0);
            z1 = fmaf(w1r[k + 1], hsv[k + 1], z1);
        }
        const float z = fmaxf(z0 + z1, 0.0f);
        float lgv = b2v;
        #pragma unroll
        for (int f = 0; f < FFD; ++f) lgv = fmaf(w2r[f], rl(z, f), lgv);
        const float mn = fmaxf(mrun, lgv);
        srun = fmaf(srun, __expf(mrun - mn), __expf(lgv - mn));
        mrun = mn;
        if (j < NCLS) out[(t_out * BB + b) * NCLS + j] = lgv;
    };

    int xvn1 = x[1 * BB + b];
    int xvn2 = x[2 * BB + b];
    float2 xg = make_float2(0.f, 0.f);
    float eA = 0.f;
    if constexpr (TAB) xg = tab[(size_t)x[b] * 64 + j];
    else               eA = emb[x[b] * EMB + m];

    if constexpr (TAB) {
        gates(xg.x, xg.y);
    } else {
        float es[EMB];
        #pragma unroll
        for (int k = 0; k < EMB; ++k) es[k] = rl(eA, k);
        float p0 = biasA, p1 = 0.f, q0 = biasB, q1 = 0.f;
        #pragma unroll
        for (int k = 0; k < EMB; k += 2) {
            p0 = fmaf(wihA[k],   es[k],   p0); p1 = fmaf(wihA[k+1], es[k+1], p1);
            q0 = fmaf(wihB[k],   es[k],   q0); q1 = fmaf(wihB[k+1], es[k+1], q1);
        }
        gates(p0 + p1, q0 + q1);
    }
    if constexpr (TAB) xg = tab[(size_t)xvn1 * 64 + j];
    else               eA = emb[xvn1 * EMB + m];
    xvn1 = xvn2;
    xvn2 = x[3 * BB + b];

    for (int t = 1; t < TT; ++t) {
        float2 xg_n = make_float2(0.f, 0.f);
        float  e_n  = 0.f;
        if (t + 1 < TT) {
            if constexpr (TAB) xg_n = tab[(size_t)xvn1 * 64 + j];
            else               e_n  = emb[xvn1 * EMB + m];
        }
        const int xv_n3 = (t + 3 < TT) ? x[(t + 3) * BB + b] : 0;

        float hsv[HID];
        #pragma unroll
        for (int k = 0; k < HID; ++k) hsv[k] = rl(h, k);

        ff_head(t - 1, hsv);

        float p0, p1 = 0.f, q0, q1 = 0.f;
        if constexpr (TAB) { p0 = xg.x; q0 = xg.y; }
        else               { p0 = biasA; q0 = biasB; }
        if constexpr (!TAB) {
            float es[EMB];
            #pragma unroll
            for (int k = 0; k < EMB; ++k) es[k] = rl(eA, k);
            #pragma unroll
            for (int k = 0; k < EMB; k += 2) {
                p0 = fmaf(wihA[k],   es[k],   p0); p1 = fmaf(wihA[k+1], es[k+1], p1);
                q0 = fmaf(wihB[k],   es[k],   q0); q1 = fmaf(wihB[k+1], es[k+1], q1);
            }
        }
        #pragma unroll
        for (int k = 0; k < HID; k += 2) {
            p0 = fmaf(whhA[k],   hsv[k],   p0); p1 = fmaf(whhA[k+1], hsv[k+1], p1);
            q0 = fmaf(whhB[k],   hsv[k],   q0); q1 = fmaf(whhB[k+1], hsv[k+1], q1);
        }
        gates(p0 + p1, q0 + q1);

        xg = xg_n; eA = e_n; xvn1 = xvn2; xvn2 = xv_n3;
    }

    {
        float hsv[HID];
        #pragma unroll
        for (int k = 0; k < HID; ++k) hsv[k] = rl(h, k);
        ff_head(TT - 1, hsv);
    }

    #pragma unroll 1
    for (int cc = 0; cc < NCLS; ++cc) {
        const float mc = rl(mrun, cc);
        const float sc = rl(srun, cc);
        const float ic = 1.0f / sc;
        #pragma unroll
        for (int i = 0; i < TT / 64; ++i) {
            const int t = j + 64 * i;
            const int a = (t * BB + b) * NCLS + cc;
            out[a] = __expf(out[a] - mc) * ic;
        }
    }
}

extern "C" void kernel_launch(void* const* d_in, const int* in_sizes, int n_in,
                              void* d_out, int out_size, void* d_ws, size_t ws_size,
                              hipStream_t stream) {
    const int*   x   = (const int*)  d_in[0];
    const float* emb = (const float*)d_in[1];
    const float* Wih = (const float*)d_in[2];
    const float* Whh = (const float*)d_in[3];
    const float* bih = (const float*)d_in[4];
    const float* bhh = (const float*)d_in[5];
    const float* W1  = (const float*)d_in[6];
    const float* b1  = (const float*)d_in[7];
    const float* W2  = (const float*)d_in[8];
    const float* b2  = (const float*)d_in[9];
    float* out = (float*)d_out;

    const size_t tab_bytes = (size_t)VOCABN * 128 * sizeof(float);   // 512 000
    const size_t hs_off    = 524288;                                 // 512 KiB align
    const size_t hs_bytes  = (size_t)BB * TT * HID * sizeof(float);  // 32 MiB
    if (ws_size >= hs_off + hs_bytes) {
        float2* tab = (float2*)d_ws;
        float*  hs  = (float*)((char*)d_ws + hs_off);
        build_xg<<<VOCABN, 64, 0, stream>>>(emb, Wih, bih, bhh, tab, 1);
        lstm_recp<<<BB / 2, 64, 0, stream>>>(x, tab, Whh, hs);
        ff_softmax<<<BB, 256, 0, stream>>>(hs, W1, b1, W2, b2, out);
    } else if (ws_size >= tab_bytes) {
        float2* tab = (float2*)d_ws;
        build_xg<<<VOCABN, 64, 0, stream>>>(emb, Wih, bih, bhh, tab, 0);
        lstm_all<true><<<BB, 64, 0, stream>>>(x, emb, Wih, Whh, bih, bhh,
                                              W1, b1, W2, b2, tab, out);
    } else {
        lstm_all<false><<<BB, 64, 0, stream>>>(x, emb, Wih, Whh, bih, bhh,
                                               W1, b1, W2, b2, nullptr, out);
    }
}